// Round 8
// baseline (1146.061 us; speedup 1.0000x reference)
//
#include <hip/hip_runtime.h>
#include <hip/hip_bf16.h>

struct f4 { float x, y, z, w; };
__device__ __forceinline__ f4 ld4(const float* p) { return *(const f4*)p; }
__device__ __forceinline__ void st4(float* p, f4 v) { *(f4*)p = v; }
__device__ __forceinline__ void acc4(f4& a, f4 b) { a.x += b.x; a.y += b.y; a.z += b.z; a.w += b.w; }

// ---------------- graph prep ----------------

__global__ void count_kernel(const int* __restrict__ col, int* __restrict__ cnt, int E) {
    int i = blockIdx.x * 256 + threadIdx.x;
    int e0 = i * 4;
    if (e0 + 4 <= E) {
        int4 c = *(const int4*)(col + e0);
        atomicAdd(&cnt[c.x], 1);
        atomicAdd(&cnt[c.y], 1);
        atomicAdd(&cnt[c.z], 1);
        atomicAdd(&cnt[c.w], 1);
    } else {
        for (int e = e0; e < E; ++e) atomicAdd(&cnt[col[e]], 1);
    }
}

// ---- device-wide exclusive scan of cnt[0..n) -> ptr[0..n], 3 passes ----

__global__ void scan1_kernel(const int* __restrict__ cnt, int* __restrict__ bsum, int n) {
    __shared__ int red[256];
    int t = threadIdx.x;
    int i = blockIdx.x * 256 + t;
    red[t] = (i < n) ? cnt[i] : 0;
    __syncthreads();
    for (int off = 128; off > 0; off >>= 1) {
        if (t < off) red[t] += red[t + off];
        __syncthreads();
    }
    if (t == 0) bsum[blockIdx.x] = red[0];
}

__global__ void scan2_kernel(int* __restrict__ bsum, int nb) {
    __shared__ int s[1024];
    int t = threadIdx.x;
    int v = (t < nb) ? bsum[t] : 0;
    s[t] = v;
    __syncthreads();
    for (int off = 1; off < 1024; off <<= 1) {
        int u = (t >= off) ? s[t - off] : 0;
        __syncthreads();
        s[t] += u;
        __syncthreads();
    }
    if (t < nb) bsum[t] = s[t] - v;   // exclusive
}

__global__ void scan3_kernel(const int* __restrict__ cnt, const int* __restrict__ bsum,
                             int* __restrict__ ptr, int n) {
    __shared__ int s[256];
    int t = threadIdx.x;
    int i = blockIdx.x * 256 + t;
    int v = (i < n) ? cnt[i] : 0;
    s[t] = v;
    __syncthreads();
    for (int off = 1; off < 256; off <<= 1) {
        int u = (t >= off) ? s[t - off] : 0;
        __syncthreads();
        s[t] += u;
        __syncthreads();
    }
    int excl = s[t] - v + bsum[blockIdx.x];
    if (i < n) ptr[i] = excl;
    if (i == n - 1) ptr[n] = excl + v;
}

__global__ void dinv_fill_kernel(const int* __restrict__ cnt, const int* __restrict__ ptr,
                                 float* __restrict__ dinv, int* __restrict__ fillp, int n) {
    int i = blockIdx.x * 256 + threadIdx.x;
    if (i >= n) return;
    dinv[i] = rsqrtf((float)(cnt[i] + 1));   // deg includes self-loop, always >=1
    fillp[i] = ptr[i];
}

__global__ void fill_kernel(const int* __restrict__ row, const int* __restrict__ col,
                            int* __restrict__ fillp, int* __restrict__ csr_row, int E) {
    int i = blockIdx.x * 256 + threadIdx.x;
    int e0 = i * 4;
    if (e0 + 4 <= E) {
        int4 c = *(const int4*)(col + e0);
        int4 r = *(const int4*)(row + e0);
        int p0 = atomicAdd(&fillp[c.x], 1);
        int p1 = atomicAdd(&fillp[c.y], 1);
        int p2 = atomicAdd(&fillp[c.z], 1);
        int p3 = atomicAdd(&fillp[c.w], 1);
        csr_row[p0] = r.x; csr_row[p1] = r.y; csr_row[p2] = r.z; csr_row[p3] = r.w;
    } else {
        for (int e = e0; e < E; ++e) {
            int p = atomicAdd(&fillp[col[e]], 1);
            csr_row[p] = row[e];
        }
    }
}

// ---------------- dense GEMM: C[n,FOUT] = (A[n,K] @ W[K,FOUT]) * scale[row] ----------------

template<int K, int FOUT>
__global__ __launch_bounds__(256) void gemm_kernel(const float* __restrict__ A,
                            const float* __restrict__ W, const float* __restrict__ scale,
                            float* __restrict__ C, int n) {
    constexpr int ROWS = 64;
    constexpr int NCG = FOUT / 4;       // column groups (4 cols each)
    constexpr int RG  = 256 / NCG;      // row groups
    constexpr int RPT = ROWS / RG;      // rows per thread
    __shared__ float As[ROWS * K];
    int t = threadIdx.x;
    int r0 = blockIdx.x * ROWS;
    for (int i = t; i < ROWS * K / 4; i += 256) {
        int idx = i * 4;
        int r = r0 + idx / K;
        f4 v;
        if (r < n) v = ld4(A + (size_t)r0 * K + idx);
        else { v.x = v.y = v.z = v.w = 0.f; }
        st4(As + idx, v);
    }
    __syncthreads();
    int cg = t % NCG, rg = t / NCG;
    int c = cg * 4, rb = rg * RPT;
    f4 acc[RPT];
#pragma unroll
    for (int i = 0; i < RPT; ++i) { acc[i].x = acc[i].y = acc[i].z = acc[i].w = 0.f; }
    for (int k = 0; k < K; k += 4) {
        f4 w0 = ld4(W + (size_t)(k + 0) * FOUT + c);
        f4 w1 = ld4(W + (size_t)(k + 1) * FOUT + c);
        f4 w2 = ld4(W + (size_t)(k + 2) * FOUT + c);
        f4 w3 = ld4(W + (size_t)(k + 3) * FOUT + c);
#pragma unroll
        for (int i = 0; i < RPT; ++i) {
            f4 a = ld4(As + (rb + i) * K + k);
            acc[i].x += a.x * w0.x + a.y * w1.x + a.z * w2.x + a.w * w3.x;
            acc[i].y += a.x * w0.y + a.y * w1.y + a.z * w2.y + a.w * w3.y;
            acc[i].z += a.x * w0.z + a.y * w1.z + a.z * w2.z + a.w * w3.z;
            acc[i].w += a.x * w0.w + a.y * w1.w + a.z * w2.w + a.w * w3.w;
        }
    }
#pragma unroll
    for (int i = 0; i < RPT; ++i) {
        int r = r0 + rb + i;
        if (r < n) {
            float s = scale[r];
            f4 v = acc[i];
            v.x *= s; v.y *= s; v.z *= s; v.w *= s;
            st4(C + (size_t)r * FOUT + c, v);
        }
    }
}

// ---------------- fused propagate + GEMM (512-thread blocks for occupancy) ----------------
// agg[v] = relu(dinv[v]*(sum_in Hs[r] + Hs[v]) + bias)  (built directly in LDS)
// C[v,:] = (agg[v,:] @ W) * dinv[v]
// Hs pre-scaled by dinv[row]. Optionally writes agg to global.

template<int K, int FOUT, bool WRITE_AGG>
__global__ __launch_bounds__(512, 4) void propgemm_kernel(const float* __restrict__ Hs,
                            const int* __restrict__ ptr, const int* __restrict__ rows,
                            const float* __restrict__ dinv, const float* __restrict__ bias,
                            const float* __restrict__ W, float* __restrict__ aggout,
                            float* __restrict__ C, int n) {
    constexpr int ROWS = 64;
    constexpr int BT = 512;
    __shared__ float As[ROWS * K];
    int t = threadIdx.x;
    int r0 = blockIdx.x * ROWS;

    // phase 1: aggregate ROWS nodes into As
    constexpr int L = K / 4;            // lanes per node
    constexpr int NPB = BT / L;         // nodes per pass
    int q = t % L, ln = t / L;
    const int f4i = q * 4;
    for (int p = 0; p < ROWS; p += NPB) {
        int node = r0 + p + ln;
        f4 a0;
        if (node < n) {
            a0 = ld4(Hs + (size_t)node * K + f4i);
            f4 a1, a2, a3;
            a1.x = a1.y = a1.z = a1.w = 0.f; a2 = a1; a3 = a1;
            int e0 = ptr[node], e1 = ptr[node + 1];
            int e = e0;
            for (; e + 4 <= e1; e += 4) {
                int rr0 = rows[e], rr1 = rows[e+1], rr2 = rows[e+2], rr3 = rows[e+3];
                acc4(a0, ld4(Hs + (size_t)rr0 * K + f4i));
                acc4(a1, ld4(Hs + (size_t)rr1 * K + f4i));
                acc4(a2, ld4(Hs + (size_t)rr2 * K + f4i));
                acc4(a3, ld4(Hs + (size_t)rr3 * K + f4i));
            }
            for (; e < e1; ++e) acc4(a0, ld4(Hs + (size_t)rows[e] * K + f4i));
            acc4(a0, a1); acc4(a2, a3); acc4(a0, a2);
            float dn = dinv[node];
            f4 b = ld4(bias + f4i);
            a0.x = fmaxf(a0.x * dn + b.x, 0.f);
            a0.y = fmaxf(a0.y * dn + b.y, 0.f);
            a0.z = fmaxf(a0.z * dn + b.z, 0.f);
            a0.w = fmaxf(a0.w * dn + b.w, 0.f);
            if (WRITE_AGG) st4(aggout + (size_t)node * K + f4i, a0);
        } else { a0.x = a0.y = a0.z = a0.w = 0.f; }
        st4(As + (p + ln) * K + f4i, a0);
    }
    __syncthreads();

    // phase 2: GEMM from As
    constexpr int NCG = FOUT / 4;
    constexpr int RG  = BT / NCG;
    constexpr int RPT = ROWS / RG;
    int cg = t % NCG, rg = t / NCG;
    int c = cg * 4, rb = rg * RPT;
    f4 acc[RPT];
#pragma unroll
    for (int i = 0; i < RPT; ++i) { acc[i].x = acc[i].y = acc[i].z = acc[i].w = 0.f; }
    for (int k = 0; k < K; k += 4) {
        f4 w0 = ld4(W + (size_t)(k + 0) * FOUT + c);
        f4 w1 = ld4(W + (size_t)(k + 1) * FOUT + c);
        f4 w2 = ld4(W + (size_t)(k + 2) * FOUT + c);
        f4 w3 = ld4(W + (size_t)(k + 3) * FOUT + c);
#pragma unroll
        for (int i = 0; i < RPT; ++i) {
            f4 a = ld4(As + (rb + i) * K + k);
            acc[i].x += a.x * w0.x + a.y * w1.x + a.z * w2.x + a.w * w3.x;
            acc[i].y += a.x * w0.y + a.y * w1.y + a.z * w2.y + a.w * w3.y;
            acc[i].z += a.x * w0.z + a.y * w1.z + a.z * w2.z + a.w * w3.z;
            acc[i].w += a.x * w0.w + a.y * w1.w + a.z * w2.w + a.w * w3.w;
        }
    }
#pragma unroll
    for (int i = 0; i < RPT; ++i) {
        int r = r0 + rb + i;
        if (r < n) {
            float s = dinv[r];
            f4 v = acc[i];
            v.x *= s; v.y *= s; v.z *= s; v.w *= s;
            st4(C + (size_t)r * FOUT + c, v);
        }
    }
}

// ---------------- fused propagate(32) + dot with W[32] ----------------

__global__ __launch_bounds__(256) void propdot_kernel(const float* __restrict__ Hs,
                            const int* __restrict__ ptr, const int* __restrict__ rows,
                            const float* __restrict__ dinv, const float* __restrict__ bias,
                            const float* __restrict__ W, float* __restrict__ outv, int n) {
    int t = threadIdx.x;
    int q = t & 7;              // 8 lanes per node (8*4 = 32)
    int ln = t >> 3;            // 32 nodes per block
    int node = blockIdx.x * 32 + ln;
    if (node >= n) return;
    const int f4i = q * 4;
    f4 a0 = ld4(Hs + (size_t)node * 32 + f4i);
    f4 a1, a2, a3;
    a1.x = a1.y = a1.z = a1.w = 0.f; a2 = a1; a3 = a1;
    int e0 = ptr[node], e1 = ptr[node + 1];
    int e = e0;
    for (; e + 4 <= e1; e += 4) {
        int rr0 = rows[e], rr1 = rows[e+1], rr2 = rows[e+2], rr3 = rows[e+3];
        acc4(a0, ld4(Hs + (size_t)rr0 * 32 + f4i));
        acc4(a1, ld4(Hs + (size_t)rr1 * 32 + f4i));
        acc4(a2, ld4(Hs + (size_t)rr2 * 32 + f4i));
        acc4(a3, ld4(Hs + (size_t)rr3 * 32 + f4i));
    }
    for (; e < e1; ++e) acc4(a0, ld4(Hs + (size_t)rows[e] * 32 + f4i));
    acc4(a0, a1); acc4(a2, a3); acc4(a0, a2);
    float dn = dinv[node];
    f4 b = ld4(bias + f4i);
    float vx = fmaxf(a0.x * dn + b.x, 0.f);
    float vy = fmaxf(a0.y * dn + b.y, 0.f);
    float vz = fmaxf(a0.z * dn + b.z, 0.f);
    float vw = fmaxf(a0.w * dn + b.w, 0.f);
    f4 w = ld4(W + f4i);
    float part = vx * w.x + vy * w.y + vz * w.z + vw * w.w;
    part += __shfl_down(part, 4, 8);
    part += __shfl_down(part, 2, 8);
    part += __shfl_down(part, 1, 8);
    if (q == 0) outv[node] = part * dn;
}

// F=1 propagate
__global__ void prop1_kernel(const float* __restrict__ Hs, const int* __restrict__ ptr,
                             const int* __restrict__ rows, const float* __restrict__ dinv,
                             const float* __restrict__ bias, float* __restrict__ out, int n) {
    int node = blockIdx.x * 256 + threadIdx.x;
    if (node >= n) return;
    float a0 = Hs[node], a1 = 0.f, a2 = 0.f, a3 = 0.f;
    int e0 = ptr[node], e1 = ptr[node + 1];
    int e = e0;
    for (; e + 4 <= e1; e += 4) {
        a0 += Hs[rows[e]];
        a1 += Hs[rows[e+1]];
        a2 += Hs[rows[e+2]];
        a3 += Hs[rows[e+3]];
    }
    for (; e < e1; ++e) a0 += Hs[rows[e]];
    float v = (a0 + a1 + a2 + a3) * dinv[node] + bias[0];
    out[node] = v > 0.f ? v : 0.f;
}

// ---------------- segment softmax + pooling (sorted batch, no atomics) ----------------

__global__ void bounds_kernel(const int* __restrict__ batch, int* __restrict__ start,
                              int n, int g_cnt) {
    int g = blockIdx.x * 256 + threadIdx.x;
    if (g > g_cnt) return;
    if (g == g_cnt) { start[g] = n; return; }
    int lo = 0, hi = n;
    while (lo < hi) { int mid = (lo + hi) >> 1; if (batch[mid] < g) lo = mid + 1; else hi = mid; }
    start[g] = lo;
}

__global__ __launch_bounds__(256) void softpool_kernel(const float* __restrict__ x,
                              const float* __restrict__ w, const int* __restrict__ start,
                              float* __restrict__ pooled) {
    int g = blockIdx.x;
    int s = start[g], e = start[g + 1];
    int t = threadIdx.x;
    __shared__ float red[256];
    float mx = -1e30f;
    for (int i = s + t; i < e; i += 256) mx = fmaxf(mx, w[i]);
    red[t] = mx; __syncthreads();
    for (int off = 128; off > 0; off >>= 1) {
        if (t < off) red[t] = fmaxf(red[t], red[t + off]);
        __syncthreads();
    }
    float m = (e > s) ? red[0] : 0.f;
    __syncthreads();
    float sm = 0.f;
    for (int i = s + t; i < e; i += 256) sm += expf(w[i] - m);
    red[t] = sm; __syncthreads();
    for (int off = 128; off > 0; off >>= 1) {
        if (t < off) red[t] += red[t + off];
        __syncthreads();
    }
    float denom = red[0] + 1e-16f;
    __syncthreads();
    int f = t & 127;
    int half = t >> 7;
    float acc = 0.f;
    for (int i = s + half; i < e; i += 2)
        acc += x[(size_t)i * 128 + f] * (expf(w[i] - m) / denom);
    red[t] = acc; __syncthreads();
    if (half == 0) pooled[g * 128 + f] = red[f] + red[128 + f];
}

// ---------------- final MLP ----------------

__global__ void mlp1_kernel(const float* __restrict__ pooled, const float* __restrict__ Wm1,
                            const float* __restrict__ bm1, float* __restrict__ hidden) {
    int g = blockIdx.x, j = threadIdx.x;   // 128 threads
    __shared__ float p[128];
    p[j] = pooled[g * 128 + j];
    __syncthreads();
    float acc = bm1[j];
    for (int k = 0; k < 128; ++k) acc += p[k] * Wm1[k * 128 + j];
    hidden[g * 128 + j] = acc > 0.f ? acc : 0.f;
}

__global__ void mlp2_kernel(const float* __restrict__ hidden, const float* __restrict__ Wm2,
                            const float* __restrict__ bm2, float* __restrict__ out) {
    int g = blockIdx.x, j = threadIdx.x;   // 256 threads
    __shared__ float h[128];
    if (j < 128) h[j] = hidden[g * 128 + j];
    __syncthreads();
    float acc = bm2[j];
    for (int k = 0; k < 128; ++k) acc += h[k] * Wm2[k * 256 + j];
    out[g * 256 + j] = acc;
}

// ---------------- launch ----------------

extern "C" void kernel_launch(void* const* d_in, const int* in_sizes, int n_in,
                              void* d_out, int out_size, void* d_ws, size_t ws_size,
                              hipStream_t stream) {
    const float* x    = (const float*)d_in[0];
    const int*   ei   = (const int*)d_in[1];
    const int*   batch= (const int*)d_in[2];
    const float* W1 = (const float*)d_in[3];  const float* b1 = (const float*)d_in[4];
    const float* W2 = (const float*)d_in[5];  const float* b2 = (const float*)d_in[6];
    const float* W3 = (const float*)d_in[7];  const float* b3 = (const float*)d_in[8];
    const float* Wa1= (const float*)d_in[9];  const float* ba1= (const float*)d_in[10];
    const float* Wa2= (const float*)d_in[11]; const float* ba2= (const float*)d_in[12];
    const float* Wa3= (const float*)d_in[13]; const float* ba3= (const float*)d_in[14];
    const float* Wm1= (const float*)d_in[15]; const float* bm1= (const float*)d_in[16];
    const float* Wm2= (const float*)d_in[17]; const float* bm2= (const float*)d_in[18];
    float* out = (float*)d_out;

    const int N = in_sizes[0] / 128;
    const int E = in_sizes[1] / 2;
    const int G = out_size / 256;

    const int* row = ei;        // edge_index[0]
    const int* col = ei + E;    // edge_index[1]

    char* wp = (char*)d_ws;
    auto alloc = [&](size_t bytes) {
        void* p = wp;
        wp += (bytes + 255) & ~(size_t)255;
        return p;
    };
    const int NB256 = (N + 255) / 256;
    int*   cnt     = (int*)alloc((size_t)N * 4);
    int*   ptr     = (int*)alloc((size_t)(N + 1) * 4);
    int*   bsum    = (int*)alloc((size_t)NB256 * 4);
    int*   fillp   = (int*)alloc((size_t)N * 4);
    int*   csr_row = (int*)alloc((size_t)E * 4);
    float* dinv    = (float*)alloc((size_t)N * 4);
    float* bufA    = (float*)alloc((size_t)N * 128 * 4);
    float* bufB    = (float*)alloc((size_t)N * 128 * 4);
    float* a64_lin = (float*)alloc((size_t)N * 64 * 4);
    float* a32_lin = (float*)alloc((size_t)N * 32 * 4);
    float* wb0     = (float*)alloc((size_t)N * 4);
    float* wb1     = (float*)alloc((size_t)N * 4);
    int*   gstart  = (int*)alloc((size_t)(G + 1) * 4);
    float* pooled  = (float*)alloc((size_t)G * 128 * 4);
    float* hidden  = (float*)alloc((size_t)G * 128 * 4);

    hipMemsetAsync(cnt, 0, (size_t)N * 4, stream);

    const int E4B = ((E + 3) / 4 + 255) / 256;
    const int NB = NB256;

    count_kernel<<<E4B, 256, 0, stream>>>(col, cnt, E);
    scan1_kernel<<<NB, 256, 0, stream>>>(cnt, bsum, N);
    scan2_kernel<<<1, 1024, 0, stream>>>(bsum, NB);
    scan3_kernel<<<NB, 256, 0, stream>>>(cnt, bsum, ptr, N);
    dinv_fill_kernel<<<NB, 256, 0, stream>>>(cnt, ptr, dinv, fillp, N);
    fill_kernel<<<E4B, 256, 0, stream>>>(row, col, fillp, csr_row, E);
    bounds_kernel<<<(G + 256) / 256, 256, 0, stream>>>(batch, gstart, N, G);

    const int GB64 = (N + 63) / 64;

    // hs1 = (x @ W1) * dinv
    gemm_kernel<128,128><<<GB64, 256, 0, stream>>>(x, W1, dinv, bufA, N);
    // x1 = relu(prop(hs1)+b1); hs2 = (x1 @ W2) * dinv   [fused, 512t]
    propgemm_kernel<128,128,false><<<GB64, 512, 0, stream>>>(bufA, ptr, csr_row, dinv, b1, W2, nullptr, bufB, N);
    // x2 = relu(prop(hs2)+b2); hs3 = (x2 @ W3) * dinv   [fused, 512t]
    propgemm_kernel<128,128,false><<<GB64, 512, 0, stream>>>(bufB, ptr, csr_row, dinv, b2, W3, nullptr, bufA, N);
    // x3 = relu(prop(hs3)+b3) -> bufB (for softpool); ha1 = (x3 @ Wa1)*dinv   [fused, 512t]
    propgemm_kernel<128,64,true><<<GB64, 512, 0, stream>>>(bufA, ptr, csr_row, dinv, b3, Wa1, bufB, a64_lin, N);
    // a64 = relu(prop(ha1)+ba1); ha2 = (a64 @ Wa2)*dinv   [fused, 512t]
    propgemm_kernel<64,32,false><<<GB64, 512, 0, stream>>>(a64_lin, ptr, csr_row, dinv, ba1, Wa2, nullptr, a32_lin, N);
    // a32 = relu(prop(ha2)+ba2); wb0 = (a32 . Wa3)*dinv   [fused]
    propdot_kernel<<<(N + 31) / 32, 256, 0, stream>>>(a32_lin, ptr, csr_row, dinv, ba2, Wa3, wb0, N);
    // w = relu(prop(wb0)+ba3)
    prop1_kernel<<<NB, 256, 0, stream>>>(wb0, ptr, csr_row, dinv, ba3, wb1, N);

    // fused segment softmax + attention pooling
    softpool_kernel<<<G, 256, 0, stream>>>(bufB, wb1, gstart, pooled);

    // final MLP
    mlp1_kernel<<<G, 128, 0, stream>>>(pooled, Wm1, bm1, hidden);
    mlp2_kernel<<<G, 256, 0, stream>>>(hidden, Wm2, bm2, out);
}

// Round 9
// 1114.326 us; speedup vs baseline: 1.0285x; 1.0285x over previous
//
#include <hip/hip_runtime.h>
#include <hip/hip_bf16.h>

struct f4 { float x, y, z, w; };
__device__ __forceinline__ f4 ld4(const float* p) { return *(const f4*)p; }
__device__ __forceinline__ void st4(float* p, f4 v) { *(f4*)p = v; }
__device__ __forceinline__ void acc4(f4& a, f4 b) { a.x += b.x; a.y += b.y; a.z += b.z; a.w += b.w; }

// ---------------- graph prep ----------------

__global__ void count_kernel(const int* __restrict__ col, int* __restrict__ cnt, int E) {
    int i = blockIdx.x * 256 + threadIdx.x;
    int e0 = i * 4;
    if (e0 + 4 <= E) {
        int4 c = *(const int4*)(col + e0);
        atomicAdd(&cnt[c.x], 1);
        atomicAdd(&cnt[c.y], 1);
        atomicAdd(&cnt[c.z], 1);
        atomicAdd(&cnt[c.w], 1);
    } else {
        for (int e = e0; e < E; ++e) atomicAdd(&cnt[col[e]], 1);
    }
}

// ---- device-wide exclusive scan of cnt[0..n) -> ptr[0..n], 3 passes ----

__global__ void scan1_kernel(const int* __restrict__ cnt, int* __restrict__ bsum, int n) {
    __shared__ int red[256];
    int t = threadIdx.x;
    int i = blockIdx.x * 256 + t;
    red[t] = (i < n) ? cnt[i] : 0;
    __syncthreads();
    for (int off = 128; off > 0; off >>= 1) {
        if (t < off) red[t] += red[t + off];
        __syncthreads();
    }
    if (t == 0) bsum[blockIdx.x] = red[0];
}

__global__ void scan2_kernel(int* __restrict__ bsum, int nb) {
    __shared__ int s[1024];
    int t = threadIdx.x;
    int v = (t < nb) ? bsum[t] : 0;
    s[t] = v;
    __syncthreads();
    for (int off = 1; off < 1024; off <<= 1) {
        int u = (t >= off) ? s[t - off] : 0;
        __syncthreads();
        s[t] += u;
        __syncthreads();
    }
    if (t < nb) bsum[t] = s[t] - v;   // exclusive
}

__global__ void scan3_kernel(const int* __restrict__ cnt, const int* __restrict__ bsum,
                             int* __restrict__ ptr, int n) {
    __shared__ int s[256];
    int t = threadIdx.x;
    int i = blockIdx.x * 256 + t;
    int v = (i < n) ? cnt[i] : 0;
    s[t] = v;
    __syncthreads();
    for (int off = 1; off < 256; off <<= 1) {
        int u = (t >= off) ? s[t - off] : 0;
        __syncthreads();
        s[t] += u;
        __syncthreads();
    }
    int excl = s[t] - v + bsum[blockIdx.x];
    if (i < n) ptr[i] = excl;
    if (i == n - 1) ptr[n] = excl + v;
}

__global__ void dinv_fill_kernel(const int* __restrict__ cnt, const int* __restrict__ ptr,
                                 float* __restrict__ dinv, int* __restrict__ fillp, int n) {
    int i = blockIdx.x * 256 + threadIdx.x;
    if (i >= n) return;
    dinv[i] = rsqrtf((float)(cnt[i] + 1));   // deg includes self-loop, always >=1
    fillp[i] = ptr[i];
}

__global__ void fill_kernel(const int* __restrict__ row, const int* __restrict__ col,
                            int* __restrict__ fillp, int* __restrict__ csr_row, int E) {
    int i = blockIdx.x * 256 + threadIdx.x;
    int e0 = i * 4;
    if (e0 + 4 <= E) {
        int4 c = *(const int4*)(col + e0);
        int4 r = *(const int4*)(row + e0);
        int p0 = atomicAdd(&fillp[c.x], 1);
        int p1 = atomicAdd(&fillp[c.y], 1);
        int p2 = atomicAdd(&fillp[c.z], 1);
        int p3 = atomicAdd(&fillp[c.w], 1);
        csr_row[p0] = r.x; csr_row[p1] = r.y; csr_row[p2] = r.z; csr_row[p3] = r.w;
    } else {
        for (int e = e0; e < E; ++e) {
            int p = atomicAdd(&fillp[col[e]], 1);
            csr_row[p] = row[e];
        }
    }
}

// ---------------- dense GEMM: C[n,FOUT] = (A[n,K] @ W[K,FOUT]) * scale[row] ----------------
// ROWS=32 tile: 3125 blocks -> high CU residency

template<int K, int FOUT>
__global__ __launch_bounds__(256) void gemm_kernel(const float* __restrict__ A,
                            const float* __restrict__ W, const float* __restrict__ scale,
                            float* __restrict__ C, int n) {
    constexpr int ROWS = 32;
    constexpr int NCG = FOUT / 4;       // column groups (4 cols each)
    constexpr int RG  = 256 / NCG;      // row groups
    constexpr int RPT = ROWS / RG;      // rows per thread
    __shared__ float As[ROWS * K];
    int t = threadIdx.x;
    int r0 = blockIdx.x * ROWS;
    for (int i = t; i < ROWS * K / 4; i += 256) {
        int idx = i * 4;
        int r = r0 + idx / K;
        f4 v;
        if (r < n) v = ld4(A + (size_t)r0 * K + idx);
        else { v.x = v.y = v.z = v.w = 0.f; }
        st4(As + idx, v);
    }
    __syncthreads();
    int cg = t % NCG, rg = t / NCG;
    int c = cg * 4, rb = rg * RPT;
    f4 acc[RPT];
#pragma unroll
    for (int i = 0; i < RPT; ++i) { acc[i].x = acc[i].y = acc[i].z = acc[i].w = 0.f; }
    for (int k = 0; k < K; k += 4) {
        f4 w0 = ld4(W + (size_t)(k + 0) * FOUT + c);
        f4 w1 = ld4(W + (size_t)(k + 1) * FOUT + c);
        f4 w2 = ld4(W + (size_t)(k + 2) * FOUT + c);
        f4 w3 = ld4(W + (size_t)(k + 3) * FOUT + c);
#pragma unroll
        for (int i = 0; i < RPT; ++i) {
            f4 a = ld4(As + (rb + i) * K + k);
            acc[i].x += a.x * w0.x + a.y * w1.x + a.z * w2.x + a.w * w3.x;
            acc[i].y += a.x * w0.y + a.y * w1.y + a.z * w2.y + a.w * w3.y;
            acc[i].z += a.x * w0.z + a.y * w1.z + a.z * w2.z + a.w * w3.z;
            acc[i].w += a.x * w0.w + a.y * w1.w + a.z * w2.w + a.w * w3.w;
        }
    }
#pragma unroll
    for (int i = 0; i < RPT; ++i) {
        int r = r0 + rb + i;
        if (r < n) {
            float s = scale[r];
            f4 v = acc[i];
            v.x *= s; v.y *= s; v.z *= s; v.w *= s;
            st4(C + (size_t)r * FOUT + c, v);
        }
    }
}

// ---------------- fused propagate + GEMM (256t, ROWS=32 for residency) ----------------
// agg[v] = relu(dinv[v]*(sum_in Hs[r] + Hs[v]) + bias)  (built directly in LDS)
// C[v,:] = (agg[v,:] @ W) * dinv[v]
// Hs pre-scaled by dinv[row]. Optionally writes agg to global.

template<int K, int FOUT, bool WRITE_AGG>
__global__ __launch_bounds__(256) void propgemm_kernel(const float* __restrict__ Hs,
                            const int* __restrict__ ptr, const int* __restrict__ rows,
                            const float* __restrict__ dinv, const float* __restrict__ bias,
                            const float* __restrict__ W, float* __restrict__ aggout,
                            float* __restrict__ C, int n) {
    constexpr int ROWS = 32;
    constexpr int BT = 256;
    __shared__ float As[ROWS * K];
    int t = threadIdx.x;
    int r0 = blockIdx.x * ROWS;

    // phase 1: aggregate ROWS nodes into As
    constexpr int L = K / 4;            // lanes per node
    constexpr int NPB = BT / L;         // nodes per pass
    int q = t % L, ln = t / L;
    const int f4i = q * 4;
    for (int p = 0; p < ROWS; p += NPB) {
        int node = r0 + p + ln;
        f4 a0;
        if (node < n) {
            a0 = ld4(Hs + (size_t)node * K + f4i);
            f4 a1, a2, a3;
            a1.x = a1.y = a1.z = a1.w = 0.f; a2 = a1; a3 = a1;
            int e0 = ptr[node], e1 = ptr[node + 1];
            int e = e0;
            for (; e + 4 <= e1; e += 4) {
                int rr0 = rows[e], rr1 = rows[e+1], rr2 = rows[e+2], rr3 = rows[e+3];
                acc4(a0, ld4(Hs + (size_t)rr0 * K + f4i));
                acc4(a1, ld4(Hs + (size_t)rr1 * K + f4i));
                acc4(a2, ld4(Hs + (size_t)rr2 * K + f4i));
                acc4(a3, ld4(Hs + (size_t)rr3 * K + f4i));
            }
            for (; e < e1; ++e) acc4(a0, ld4(Hs + (size_t)rows[e] * K + f4i));
            acc4(a0, a1); acc4(a2, a3); acc4(a0, a2);
            float dn = dinv[node];
            f4 b = ld4(bias + f4i);
            a0.x = fmaxf(a0.x * dn + b.x, 0.f);
            a0.y = fmaxf(a0.y * dn + b.y, 0.f);
            a0.z = fmaxf(a0.z * dn + b.z, 0.f);
            a0.w = fmaxf(a0.w * dn + b.w, 0.f);
            if (WRITE_AGG) st4(aggout + (size_t)node * K + f4i, a0);
        } else { a0.x = a0.y = a0.z = a0.w = 0.f; }
        st4(As + (p + ln) * K + f4i, a0);
    }
    __syncthreads();

    // phase 2: GEMM from As
    constexpr int NCG = FOUT / 4;
    constexpr int RG  = BT / NCG;
    constexpr int RPT = ROWS / RG;
    int cg = t % NCG, rg = t / NCG;
    int c = cg * 4, rb = rg * RPT;
    f4 acc[RPT];
#pragma unroll
    for (int i = 0; i < RPT; ++i) { acc[i].x = acc[i].y = acc[i].z = acc[i].w = 0.f; }
    for (int k = 0; k < K; k += 4) {
        f4 w0 = ld4(W + (size_t)(k + 0) * FOUT + c);
        f4 w1 = ld4(W + (size_t)(k + 1) * FOUT + c);
        f4 w2 = ld4(W + (size_t)(k + 2) * FOUT + c);
        f4 w3 = ld4(W + (size_t)(k + 3) * FOUT + c);
#pragma unroll
        for (int i = 0; i < RPT; ++i) {
            f4 a = ld4(As + (rb + i) * K + k);
            acc[i].x += a.x * w0.x + a.y * w1.x + a.z * w2.x + a.w * w3.x;
            acc[i].y += a.x * w0.y + a.y * w1.y + a.z * w2.y + a.w * w3.y;
            acc[i].z += a.x * w0.z + a.y * w1.z + a.z * w2.z + a.w * w3.z;
            acc[i].w += a.x * w0.w + a.y * w1.w + a.z * w2.w + a.w * w3.w;
        }
    }
#pragma unroll
    for (int i = 0; i < RPT; ++i) {
        int r = r0 + rb + i;
        if (r < n) {
            float s = dinv[r];
            f4 v = acc[i];
            v.x *= s; v.y *= s; v.z *= s; v.w *= s;
            st4(C + (size_t)r * FOUT + c, v);
        }
    }
}

// ---------------- fused propagate(32) + dot with W[32] ----------------

__global__ __launch_bounds__(256) void propdot_kernel(const float* __restrict__ Hs,
                            const int* __restrict__ ptr, const int* __restrict__ rows,
                            const float* __restrict__ dinv, const float* __restrict__ bias,
                            const float* __restrict__ W, float* __restrict__ outv, int n) {
    int t = threadIdx.x;
    int q = t & 7;              // 8 lanes per node (8*4 = 32)
    int ln = t >> 3;            // 32 nodes per block
    int node = blockIdx.x * 32 + ln;
    if (node >= n) return;
    const int f4i = q * 4;
    f4 a0 = ld4(Hs + (size_t)node * 32 + f4i);
    f4 a1, a2, a3;
    a1.x = a1.y = a1.z = a1.w = 0.f; a2 = a1; a3 = a1;
    int e0 = ptr[node], e1 = ptr[node + 1];
    int e = e0;
    for (; e + 4 <= e1; e += 4) {
        int rr0 = rows[e], rr1 = rows[e+1], rr2 = rows[e+2], rr3 = rows[e+3];
        acc4(a0, ld4(Hs + (size_t)rr0 * 32 + f4i));
        acc4(a1, ld4(Hs + (size_t)rr1 * 32 + f4i));
        acc4(a2, ld4(Hs + (size_t)rr2 * 32 + f4i));
        acc4(a3, ld4(Hs + (size_t)rr3 * 32 + f4i));
    }
    for (; e < e1; ++e) acc4(a0, ld4(Hs + (size_t)rows[e] * 32 + f4i));
    acc4(a0, a1); acc4(a2, a3); acc4(a0, a2);
    float dn = dinv[node];
    f4 b = ld4(bias + f4i);
    float vx = fmaxf(a0.x * dn + b.x, 0.f);
    float vy = fmaxf(a0.y * dn + b.y, 0.f);
    float vz = fmaxf(a0.z * dn + b.z, 0.f);
    float vw = fmaxf(a0.w * dn + b.w, 0.f);
    f4 w = ld4(W + f4i);
    float part = vx * w.x + vy * w.y + vz * w.z + vw * w.w;
    part += __shfl_down(part, 4, 8);
    part += __shfl_down(part, 2, 8);
    part += __shfl_down(part, 1, 8);
    if (q == 0) outv[node] = part * dn;
}

// F=1 propagate
__global__ void prop1_kernel(const float* __restrict__ Hs, const int* __restrict__ ptr,
                             const int* __restrict__ rows, const float* __restrict__ dinv,
                             const float* __restrict__ bias, float* __restrict__ out, int n) {
    int node = blockIdx.x * 256 + threadIdx.x;
    if (node >= n) return;
    float a0 = Hs[node], a1 = 0.f, a2 = 0.f, a3 = 0.f;
    int e0 = ptr[node], e1 = ptr[node + 1];
    int e = e0;
    for (; e + 4 <= e1; e += 4) {
        a0 += Hs[rows[e]];
        a1 += Hs[rows[e+1]];
        a2 += Hs[rows[e+2]];
        a3 += Hs[rows[e+3]];
    }
    for (; e < e1; ++e) a0 += Hs[rows[e]];
    float v = (a0 + a1 + a2 + a3) * dinv[node] + bias[0];
    out[node] = v > 0.f ? v : 0.f;
}

// ---------------- segment softmax + pooling (sorted batch, no atomics) ----------------

__global__ void bounds_kernel(const int* __restrict__ batch, int* __restrict__ start,
                              int n, int g_cnt) {
    int g = blockIdx.x * 256 + threadIdx.x;
    if (g > g_cnt) return;
    if (g == g_cnt) { start[g] = n; return; }
    int lo = 0, hi = n;
    while (lo < hi) { int mid = (lo + hi) >> 1; if (batch[mid] < g) lo = mid + 1; else hi = mid; }
    start[g] = lo;
}

__global__ __launch_bounds__(256) void softpool_kernel(const float* __restrict__ x,
                              const float* __restrict__ w, const int* __restrict__ start,
                              float* __restrict__ pooled) {
    int g = blockIdx.x;
    int s = start[g], e = start[g + 1];
    int t = threadIdx.x;
    __shared__ float red[256];
    float mx = -1e30f;
    for (int i = s + t; i < e; i += 256) mx = fmaxf(mx, w[i]);
    red[t] = mx; __syncthreads();
    for (int off = 128; off > 0; off >>= 1) {
        if (t < off) red[t] = fmaxf(red[t], red[t + off]);
        __syncthreads();
    }
    float m = (e > s) ? red[0] : 0.f;
    __syncthreads();
    float sm = 0.f;
    for (int i = s + t; i < e; i += 256) sm += expf(w[i] - m);
    red[t] = sm; __syncthreads();
    for (int off = 128; off > 0; off >>= 1) {
        if (t < off) red[t] += red[t + off];
        __syncthreads();
    }
    float denom = red[0] + 1e-16f;
    __syncthreads();
    int f = t & 127;
    int half = t >> 7;
    float acc = 0.f;
    for (int i = s + half; i < e; i += 2)
        acc += x[(size_t)i * 128 + f] * (expf(w[i] - m) / denom);
    red[t] = acc; __syncthreads();
    if (half == 0) pooled[g * 128 + f] = red[f] + red[128 + f];
}

// ---------------- final MLP ----------------

__global__ void mlp1_kernel(const float* __restrict__ pooled, const float* __restrict__ Wm1,
                            const float* __restrict__ bm1, float* __restrict__ hidden) {
    int g = blockIdx.x, j = threadIdx.x;   // 128 threads
    __shared__ float p[128];
    p[j] = pooled[g * 128 + j];
    __syncthreads();
    float acc = bm1[j];
    for (int k = 0; k < 128; ++k) acc += p[k] * Wm1[k * 128 + j];
    hidden[g * 128 + j] = acc > 0.f ? acc : 0.f;
}

__global__ void mlp2_kernel(const float* __restrict__ hidden, const float* __restrict__ Wm2,
                            const float* __restrict__ bm2, float* __restrict__ out) {
    int g = blockIdx.x, j = threadIdx.x;   // 256 threads
    __shared__ float h[128];
    if (j < 128) h[j] = hidden[g * 128 + j];
    __syncthreads();
    float acc = bm2[j];
    for (int k = 0; k < 128; ++k) acc += h[k] * Wm2[k * 256 + j];
    out[g * 256 + j] = acc;
}

// ---------------- launch ----------------

extern "C" void kernel_launch(void* const* d_in, const int* in_sizes, int n_in,
                              void* d_out, int out_size, void* d_ws, size_t ws_size,
                              hipStream_t stream) {
    const float* x    = (const float*)d_in[0];
    const int*   ei   = (const int*)d_in[1];
    const int*   batch= (const int*)d_in[2];
    const float* W1 = (const float*)d_in[3];  const float* b1 = (const float*)d_in[4];
    const float* W2 = (const float*)d_in[5];  const float* b2 = (const float*)d_in[6];
    const float* W3 = (const float*)d_in[7];  const float* b3 = (const float*)d_in[8];
    const float* Wa1= (const float*)d_in[9];  const float* ba1= (const float*)d_in[10];
    const float* Wa2= (const float*)d_in[11]; const float* ba2= (const float*)d_in[12];
    const float* Wa3= (const float*)d_in[13]; const float* ba3= (const float*)d_in[14];
    const float* Wm1= (const float*)d_in[15]; const float* bm1= (const float*)d_in[16];
    const float* Wm2= (const float*)d_in[17]; const float* bm2= (const float*)d_in[18];
    float* out = (float*)d_out;

    const int N = in_sizes[0] / 128;
    const int E = in_sizes[1] / 2;
    const int G = out_size / 256;

    const int* row = ei;        // edge_index[0]
    const int* col = ei + E;    // edge_index[1]

    char* wp = (char*)d_ws;
    auto alloc = [&](size_t bytes) {
        void* p = wp;
        wp += (bytes + 255) & ~(size_t)255;
        return p;
    };
    const int NB256 = (N + 255) / 256;
    int*   cnt     = (int*)alloc((size_t)N * 4);
    int*   ptr     = (int*)alloc((size_t)(N + 1) * 4);
    int*   bsum    = (int*)alloc((size_t)NB256 * 4);
    int*   fillp   = (int*)alloc((size_t)N * 4);
    int*   csr_row = (int*)alloc((size_t)E * 4);
    float* dinv    = (float*)alloc((size_t)N * 4);
    float* bufA    = (float*)alloc((size_t)N * 128 * 4);
    float* bufB    = (float*)alloc((size_t)N * 128 * 4);
    float* a64_lin = (float*)alloc((size_t)N * 64 * 4);
    float* a32_lin = (float*)alloc((size_t)N * 32 * 4);
    float* wb0     = (float*)alloc((size_t)N * 4);
    float* wb1     = (float*)alloc((size_t)N * 4);
    int*   gstart  = (int*)alloc((size_t)(G + 1) * 4);
    float* pooled  = (float*)alloc((size_t)G * 128 * 4);
    float* hidden  = (float*)alloc((size_t)G * 128 * 4);

    hipMemsetAsync(cnt, 0, (size_t)N * 4, stream);

    const int E4B = ((E + 3) / 4 + 255) / 256;
    const int NB = NB256;

    count_kernel<<<E4B, 256, 0, stream>>>(col, cnt, E);
    scan1_kernel<<<NB, 256, 0, stream>>>(cnt, bsum, N);
    scan2_kernel<<<1, 1024, 0, stream>>>(bsum, NB);
    scan3_kernel<<<NB, 256, 0, stream>>>(cnt, bsum, ptr, N);
    dinv_fill_kernel<<<NB, 256, 0, stream>>>(cnt, ptr, dinv, fillp, N);
    fill_kernel<<<E4B, 256, 0, stream>>>(row, col, fillp, csr_row, E);
    bounds_kernel<<<(G + 256) / 256, 256, 0, stream>>>(batch, gstart, N, G);

    const int GB32 = (N + 31) / 32;

    // hs1 = (x @ W1) * dinv
    gemm_kernel<128,128><<<GB32, 256, 0, stream>>>(x, W1, dinv, bufA, N);
    // x1 = relu(prop(hs1)+b1); hs2 = (x1 @ W2) * dinv   [fused]
    propgemm_kernel<128,128,false><<<GB32, 256, 0, stream>>>(bufA, ptr, csr_row, dinv, b1, W2, nullptr, bufB, N);
    // x2 = relu(prop(hs2)+b2); hs3 = (x2 @ W3) * dinv   [fused]
    propgemm_kernel<128,128,false><<<GB32, 256, 0, stream>>>(bufB, ptr, csr_row, dinv, b2, W3, nullptr, bufA, N);
    // x3 = relu(prop(hs3)+b3) -> bufB (for softpool); ha1 = (x3 @ Wa1)*dinv   [fused]
    propgemm_kernel<128,64,true><<<GB32, 256, 0, stream>>>(bufA, ptr, csr_row, dinv, b3, Wa1, bufB, a64_lin, N);
    // a64 = relu(prop(ha1)+ba1); ha2 = (a64 @ Wa2)*dinv   [fused]
    propgemm_kernel<64,32,false><<<GB32, 256, 0, stream>>>(a64_lin, ptr, csr_row, dinv, ba1, Wa2, nullptr, a32_lin, N);
    // a32 = relu(prop(ha2)+ba2); wb0 = (a32 . Wa3)*dinv   [fused]
    propdot_kernel<<<(N + 31) / 32, 256, 0, stream>>>(a32_lin, ptr, csr_row, dinv, ba2, Wa3, wb0, N);
    // w = relu(prop(wb0)+ba3)
    prop1_kernel<<<NB, 256, 0, stream>>>(wb0, ptr, csr_row, dinv, ba3, wb1, N);

    // fused segment softmax + attention pooling
    softpool_kernel<<<G, 256, 0, stream>>>(bufB, wb1, gstart, pooled);

    // final MLP
    mlp1_kernel<<<G, 128, 0, stream>>>(pooled, Wm1, bm1, hidden);
    mlp2_kernel<<<G, 256, 0, stream>>>(hidden, Wm2, bm2, out);
}